// Round 10
// baseline (69.397 us; speedup 1.0000x reference)
//
#include <hip/hip_runtime.h>

#define T_DIM 20
#define K_DIM 50
#define V_DIM 50000
#define D_DIM 200
#define NEG_TOPK 20
#define M_DIM (K_DIM * NEG_TOPK)   // 1000 candidates per time slice
#define TEMP_INV (1.0f / 0.07f)
#define POOL_CAP 512
#define STATIC_THR 3.0f            // pool keeps all elements >= 3.0

// monotone key: order(key) == (value desc, index asc) matches jax.lax.top_k
__device__ __forceinline__ unsigned long long make_key(float f, int idx) {
  unsigned u  = __float_as_uint(f);
  unsigned mv = ((int)u < 0) ? ~u : (u | 0x80000000u);
  return ((unsigned long long)mv << 32) |
         (unsigned long long)(0xFFFFFFFFu - (unsigned)idx);
}

__device__ __forceinline__ unsigned long long wave_max_u64(unsigned long long k) {
#pragma unroll
  for (int off = 32; off; off >>= 1) {
    unsigned long long o = __shfl_xor(k, off, 64);
    if (o > k) k = o;
  }
  return k;
}

// ---------------------------------------------------------------------------
// Kernel 1: exact top-20 per row = t*K+k.
// Scan: 8 independent float4 loads issued back-to-back, then
// sched_barrier(0) pins them ABOVE the branchy extraction (R7's failure:
// compiler sank the loads into the branches, 1 in flight, ~700 GB/s
// latency-bound). Loads of iter j+1 may still hoist over extraction j —
// pipeline preserved. Extraction: fmax-tree + rare LDS pool append.
// If 20<=|pool|<=512 the exact top-20 is in the pool (if >=20 elements are
// >= thr, the 20th-largest >= thr; E[|pool|]~67, Poisson). Selection on
// wave 0 only, barrier-free. Fallback (<20 or >512): exact 20-round
// block-wide rescan (cached). NO extra tail code in this kernel (R6/R7:
// appending bv/ticket code tanked regalloc to 24 VGPR).
// ---------------------------------------------------------------------------
#define NV4        (V_DIM / 4)                  // 12500
#define SCAN_STEP  (512 * 8)                    // 4096 float4 per iter
#define FULL_ITERS (NV4 / SCAN_STEP)            // 3 -> covers 12288
#define TAIL_BASE  (FULL_ITERS * SCAN_STEP)     // 12288; tail = 212

__global__ __launch_bounds__(512) void topk_kernel(const float* __restrict__ beta,
                                                   int* __restrict__ topk_idx) {
  const int row  = blockIdx.x;          // 0..999
  const int tid  = threadIdx.x;
  const int lane = tid & 63;
  const int wid  = tid >> 6;
  const float4* __restrict__ b4 = (const float4*)(beta + (size_t)row * V_DIM);

  __shared__ unsigned long long pool[POOL_CAP];
  __shared__ int cnt;
  __shared__ unsigned long long wmax[8];
  if (tid == 0) cnt = 0;
  __syncthreads();

#define APPEND(f, idx)                                                       \
  { int p = atomicAdd(&cnt, 1); if (p < POOL_CAP) pool[p] = make_key((f), (idx)); }
#define EXTRACT(vq, q)                                                       \
  {                                                                          \
    float mx = fmaxf(fmaxf(vq.x, vq.y), fmaxf(vq.z, vq.w));                  \
    if (mx >= STATIC_THR) {                                                  \
      const int base = (ib + (q) * 512) * 4;                                 \
      if (vq.x >= STATIC_THR) APPEND(vq.x, base + 0)                         \
      if (vq.y >= STATIC_THR) APPEND(vq.y, base + 1)                         \
      if (vq.z >= STATIC_THR) APPEND(vq.z, base + 2)                         \
      if (vq.w >= STATIC_THR) APPEND(vq.w, base + 3)                         \
    }                                                                        \
  }

  for (int j = 0; j < FULL_ITERS; ++j) {
    const int ib = j * SCAN_STEP + tid;
    float4 v0 = b4[ib + 0 * 512];
    float4 v1 = b4[ib + 1 * 512];
    float4 v2 = b4[ib + 2 * 512];
    float4 v3 = b4[ib + 3 * 512];
    float4 v4 = b4[ib + 4 * 512];
    float4 v5 = b4[ib + 5 * 512];
    float4 v6 = b4[ib + 6 * 512];
    float4 v7 = b4[ib + 7 * 512];
    __builtin_amdgcn_sched_barrier(0);   // loads stay ABOVE; 8 in flight
    EXTRACT(v0, 0) EXTRACT(v1, 1) EXTRACT(v2, 2) EXTRACT(v3, 3)
    EXTRACT(v4, 4) EXTRACT(v5, 5) EXTRACT(v6, 6) EXTRACT(v7, 7)
  }
  if (tid < NV4 - TAIL_BASE) {           // tail: first 212 threads
    const int ib = TAIL_BASE + tid;      // reuse EXTRACT with q=0
    float4 v0 = b4[ib];
    EXTRACT(v0, 0)
  }
#undef EXTRACT
#undef APPEND
  __syncthreads();
  const int count = cnt;

  if (count >= NEG_TOPK && count <= POOL_CAP) {
    if (wid != 0) return;              // selection is wave-0-only, no barriers
    unsigned long long kk[8];
#pragma unroll
    for (int j = 0; j < 8; ++j) {
      int p = lane + (j << 6);
      kk[j] = (p < count) ? pool[p] : 0ull;
    }
    unsigned long long kprev = ~0ull;
    for (int r = 0; r < NEG_TOPK; ++r) {
      unsigned long long b = 0ull;
#pragma unroll
      for (int j = 0; j < 8; ++j)
        if (kk[j] < kprev && kk[j] > b) b = kk[j];
      b = wave_max_u64(b);
      if (lane == 0)
        topk_idx[row * NEG_TOPK + r] =
            (int)(0xFFFFFFFFu - (unsigned)(b & 0xFFFFFFFFull));
      kprev = b;
    }
  } else {
    // ---- fallback: 20 rounds of block argmax over the row (cached) ----
    unsigned long long kprev = ~0ull;
    for (int r = 0; r < NEG_TOPK; ++r) {
      unsigned long long b = 0ull;
      for (int i = tid; i < NV4; i += 512) {
        float4 v = b4[i];
        const int base = i * 4;
#pragma unroll
        for (int e = 0; e < 4; ++e) {
          float f = (e == 0) ? v.x : (e == 1) ? v.y : (e == 2) ? v.z : v.w;
          unsigned long long k = make_key(f, base + e);
          if (k < kprev && k > b) b = k;
        }
      }
      b = wave_max_u64(b);
      if (lane == 0) wmax[wid] = b;
      __syncthreads();
      unsigned long long bmax = wmax[0];
#pragma unroll
      for (int w = 1; w < 8; ++w) bmax = wmax[w] > bmax ? wmax[w] : bmax;
      if (tid == 0)
        topk_idx[row * NEG_TOPK + r] =
            (int)(0xFFFFFFFFu - (unsigned)(bmax & 0xFFFFFFFFull));
      kprev = bmax;
      __syncthreads();
    }
  }
}

// ---------------------------------------------------------------------------
// Kernel 2: per time slice t, unique valid candidates (wc==0, set semantics;
// which duplicate survives is irrelevant — identical sim rows). R3-verbatim.
// ---------------------------------------------------------------------------
#define BM_WORDS ((V_DIM + 31) / 32)    // 1563
__global__ __launch_bounds__(256) void build_valid_kernel(const int* __restrict__ wc,
                                                          const int* __restrict__ topk,
                                                          int* __restrict__ vlist,
                                                          int* __restrict__ vcnt) {
  const int t = blockIdx.x;
  __shared__ unsigned bm[BM_WORDS];
  __shared__ int cnt;
  for (int i = threadIdx.x; i < BM_WORDS; i += 256) bm[i] = 0u;
  if (threadIdx.x == 0) cnt = 0;
  __syncthreads();
  for (int c = threadIdx.x; c < M_DIM; c += 256) {
    int w = topk[t * M_DIM + c];
    if (wc[t * V_DIM + w] == 0) {
      unsigned bit = 1u << (w & 31);
      unsigned old = atomicOr(&bm[w >> 5], bit);
      if (!(old & bit)) {
        int p = atomicAdd(&cnt, 1);
        vlist[t * M_DIM + p] = w;
      }
    }
  }
  __syncthreads();
  if (threadIdx.x == 0) vcnt[t] = cnt;
}

// ---------------------------------------------------------------------------
// Kernel 3: lse per row, XCD-pinned grid (R9, −1µs). Grid = 1200: xcd=bid&7,
// slot=bid>>3; t = xcd + 8*(slot/50), k = slot%50; t>=20 dummies exit.
// No fences/tickets (R4/R8: device-scope fences cost 12-18 µs).
// ---------------------------------------------------------------------------
__global__ __launch_bounds__(256) void lse_kernel(const float* __restrict__ temb,
                                                  const float* __restrict__ wemb,
                                                  const int* __restrict__ vlist,
                                                  const int* __restrict__ vcnt,
                                                  float* __restrict__ lse_out) {
  const int xcd  = blockIdx.x & 7;
  const int slot = blockIdx.x >> 3;
  const int t    = xcd + ((slot / K_DIM) << 3);
  if (t >= T_DIM) return;               // dummy block
  const int k    = slot % K_DIM;
  const int row  = t * K_DIM + k;
  const int tid  = threadIdx.x;
  const int lane = tid & 63;
  const int wid  = tid >> 6;
  const int cnt  = vcnt[t];

  __shared__ float4 tvs[D_DIM / 4];  // 50 float4: topic embedding row
  __shared__ float  sim[M_DIM];
  __shared__ float  rbuf[8];

  if (cnt == 0) {
    if (tid == 0) lse_out[row] = 0.0f;
    return;
  }

  if (tid < D_DIM / 4)
    tvs[tid] = ((const float4*)(temb + (size_t)row * D_DIM))[tid];
  __syncthreads();

  const int l7 = lane & 7;
  const int g  = lane >> 3;          // candidate sub-slot 0..7 within wave
  for (int c0 = wid * 8; c0 < cnt; c0 += 32) {
    const int c = c0 + g;
    float acc = 0.f;
    if (c < cnt) {
      const int w = vlist[t * M_DIM + c];
      const float4* __restrict__ wr = (const float4*)(wemb + (size_t)w * D_DIM);
#pragma unroll
      for (int m = 0; m < 6; ++m) {        // d = l7 + 8m, < 50 for m<6
        const int d = l7 + (m << 3);
        float4 a = tvs[d];
        float4 b = wr[d];
        acc = fmaf(a.x, b.x, acc);
        acc = fmaf(a.y, b.y, acc);
        acc = fmaf(a.z, b.z, acc);
        acc = fmaf(a.w, b.w, acc);
      }
      if (l7 < 2) {                        // d in {48,49}
        const int d = l7 + 48;
        float4 a = tvs[d];
        float4 b = wr[d];
        acc = fmaf(a.x, b.x, acc);
        acc = fmaf(a.y, b.y, acc);
        acc = fmaf(a.z, b.z, acc);
        acc = fmaf(a.w, b.w, acc);
      }
    }
    acc += __shfl_xor(acc, 1, 64);
    acc += __shfl_xor(acc, 2, 64);
    acc += __shfl_xor(acc, 4, 64);
    if (l7 == 0 && c < cnt) sim[c] = acc * TEMP_INV;
  }
  __syncthreads();

  float m = -3.0e38f;
  for (int c = tid; c < cnt; c += 256) m = fmaxf(m, sim[c]);
#pragma unroll
  for (int off = 32; off; off >>= 1) m = fmaxf(m, __shfl_xor(m, off, 64));
  if (lane == 0) rbuf[wid] = m;
  __syncthreads();
  m = fmaxf(fmaxf(rbuf[0], rbuf[1]), fmaxf(rbuf[2], rbuf[3]));

  float s = 0.f;
  for (int c = tid; c < cnt; c += 256) s += expf(sim[c] - m);
#pragma unroll
  for (int off = 32; off; off >>= 1) s += __shfl_xor(s, off, 64);
  if (lane == 0) rbuf[4 + wid] = s;
  __syncthreads();
  if (tid == 0) {
    float tot = rbuf[4] + rbuf[5] + rbuf[6] + rbuf[7];
    lse_out[row] = m + logf(tot);
  }
}

// ---------------------------------------------------------------------------
// Kernel 4: final scalar. loss = sum_t(mean_k lse) / count(t with any valid).
// ---------------------------------------------------------------------------
__global__ void final_kernel(const float* __restrict__ lse,
                             const int* __restrict__ vcnt,
                             float* __restrict__ out) {
  const int t = threadIdx.x;           // 64 threads, t < 20 active
  float loss = 0.f, flag = 0.f;
  if (t < T_DIM && vcnt[t] > 0) {
    float s = 0.f;
    for (int k = 0; k < K_DIM; ++k) s += lse[t * K_DIM + k];
    loss = s * (1.0f / K_DIM);
    flag = 1.f;
  }
#pragma unroll
  for (int off = 32; off; off >>= 1) {
    loss += __shfl_down(loss, off, 64);
    flag += __shfl_down(flag, off, 64);
  }
  if (t == 0)
    out[0] = (flag > 0.f) ? loss * (1.0f / fmaxf(flag, 1.f)) : 0.f;  // WEIGHT_UWE=1
}

// ---------------------------------------------------------------------------
extern "C" void kernel_launch(void* const* d_in, const int* in_sizes, int n_in,
                              void* d_out, int out_size, void* d_ws, size_t ws_size,
                              hipStream_t stream) {
  const int*   wc   = (const int*)d_in[0];    // time_wordcount [T,V] int32
  const float* beta = (const float*)d_in[1];  // beta [T,K,V] f32
  const float* temb = (const float*)d_in[2];  // topic_embeddings [T,K,D] f32
  const float* wemb = (const float*)d_in[3];  // word_embeddings [V,D] f32

  // ws layout: topk 80000B | vlist 80000B | vcnt 128B | lse 4000B
  char* ws = (char*)d_ws;
  int*   topk_idx = (int*)(ws + 0);
  int*   vlist    = (int*)(ws + 80000);
  int*   vcnt     = (int*)(ws + 160000);
  float* lse      = (float*)(ws + 160128);
  float* out      = (float*)d_out;

  topk_kernel<<<T_DIM * K_DIM, 512, 0, stream>>>(beta, topk_idx);
  build_valid_kernel<<<T_DIM, 256, 0, stream>>>(wc, topk_idx, vlist, vcnt);
  lse_kernel<<<1200, 256, 0, stream>>>(temb, wemb, vlist, vcnt, lse);
  final_kernel<<<1, 64, 0, stream>>>(lse, vcnt, out);
}